// Round 5
// baseline (179.726 us; speedup 1.0000x reference)
//
#include <hip/hip_runtime.h>
#include <stdint.h>

typedef float v4f __attribute__((ext_vector_type(4)));
typedef float v16f __attribute__((ext_vector_type(16)));
typedef int v8i __attribute__((ext_vector_type(8)));

#define FP8_DENOM 358.4f  // FP8_MAX(448) * SCALE_MARGIN(0.8)

// ---------- helpers ----------

__device__ __forceinline__ unsigned pack4_fp8(float a, float b, float c, float d) {
  // v_cvt_pk_fp8_f32: RNE, saturating (values <=358.4 by construction)
  int v = 0;
  v = __builtin_amdgcn_cvt_pk_fp8_f32(a, b, v, false);  // bytes 0,1
  v = __builtin_amdgcn_cvt_pk_fp8_f32(c, d, v, true);   // bytes 2,3
  return (unsigned)v;
}

__device__ __forceinline__ void gload_lds16(const void* g, void* l) {
  // 16B-wide async global->LDS. LDS dest must be wave-uniform base + lane*16.
  __builtin_amdgcn_global_load_lds(
      (const __attribute__((address_space(1))) uint32_t*)(uintptr_t)g,
      (__attribute__((address_space(3))) uint32_t*)(uint32_t)(uintptr_t)l,
      16, 0, 0);
}

// ---------- stage 1: per-block amax -> single atomicMax ----------
// blocks 0..1023 cover x (4096 float4 each), blocks 1024..1279 cover w.
// FROZEN (r3 form) for clean gemm A/B this round.

__global__ void __launch_bounds__(256) amax_part(const float4* __restrict__ x,
                                                 const float4* __restrict__ w,
                                                 unsigned* __restrict__ amax) {
  const int b = blockIdx.x, t = threadIdx.x;
  const int isw = (b >= 1024) ? 1 : 0;
  const float4* p = isw ? w : x;
  const long base = (long)(isw ? (b - 1024) : b) * 4096;
  float m0 = 0.f, m1 = 0.f, m2 = 0.f, m3 = 0.f;
#pragma unroll
  for (int j = 0; j < 4; ++j) {
    float4 v0 = p[base + (j * 4 + 0) * 256 + t];
    float4 v1 = p[base + (j * 4 + 1) * 256 + t];
    float4 v2 = p[base + (j * 4 + 2) * 256 + t];
    float4 v3 = p[base + (j * 4 + 3) * 256 + t];
    m0 = fmaxf(m0, fmaxf(fmaxf(fabsf(v0.x), fabsf(v0.y)), fmaxf(fabsf(v0.z), fabsf(v0.w))));
    m1 = fmaxf(m1, fmaxf(fmaxf(fabsf(v1.x), fabsf(v1.y)), fmaxf(fabsf(v1.z), fabsf(v1.w))));
    m2 = fmaxf(m2, fmaxf(fmaxf(fabsf(v2.x), fabsf(v2.y)), fmaxf(fabsf(v2.z), fabsf(v2.w))));
    m3 = fmaxf(m3, fmaxf(fmaxf(fabsf(v3.x), fabsf(v3.y)), fmaxf(fabsf(v3.z), fabsf(v3.w))));
  }
  float m = fmaxf(fmaxf(m0, m1), fmaxf(m2, m3));
#pragma unroll
  for (int off = 32; off > 0; off >>= 1)
    m = fmaxf(m, __shfl_down(m, off, 64));
  __shared__ float red[4];
  const int lane = t & 63, wvid = t >> 6;
  if (lane == 0) red[wvid] = m;
  __syncthreads();
  if (t == 0)
    atomicMax(amax + isw,
              __float_as_uint(fmaxf(fmaxf(red[0], red[1]), fmaxf(red[2], red[3]))));
}

// ---------- stage 2: fused quantize x and w -> fp8 e4m3fn codes ----------
// FROZEN (r3 form). Coalesced per-lane float4 reads, packed unsigned writes.

__global__ void __launch_bounds__(256) quant2_kernel(
    const float4* __restrict__ x, unsigned* __restrict__ xq,
    const float4* __restrict__ w, unsigned* __restrict__ wq,
    const unsigned* __restrict__ amax) {
  const int t = threadIdx.x;
  const int isw = ((int)blockIdx.x >= 4096) ? 1 : 0;
  const float ax = __uint_as_float(amax[0]);
  const float aw = __uint_as_float(amax[1]);
  const float s = (isw ? fmaxf(ax, aw) : ax) / FP8_DENOM;  // shared amax history max for w
  const float rs = 1.0f / s;
  const float4* in = isw ? w : x;
  unsigned* outq = isw ? wq : xq;
  const long base = (long)(isw ? ((int)blockIdx.x - 4096) : (int)blockIdx.x) * 1024;
#pragma unroll
  for (int j = 0; j < 4; ++j) {
    float4 v = in[base + j * 256 + t];
    outq[base + j * 256 + t] = pack4_fp8(v.x * rs, v.y * rs, v.z * rs, v.w * rs);
  }
}

// ---------- MX-scaled fp8 GEMM: 128x128, BK=64, 4 blocks/CU -------------
// M=8192 N=2048 K=2048. r0-r4 post-mortem: five schedule variants all land at
// ~35% of MX ceiling (the documented 2-barrier-structure ceiling), all with
// exactly 2 waves/SIMD in lockstep. Untested axis = TLP. This version:
//  - 256 thr (2x2 waves, 64x64/wave), mfma_scale_f32_32x32x64 (same 4686 TF
//    rate, acc = 64 AGPR not 128 -> total regs <=128)
//  - LDS 32KB/block (2dbuf x (8KB A + 8KB B)) -> 4 co-resident blocks/CU
//    = 16 waves/CU = 4 waves/SIMD, 4 independent barrier domains per CU
//    (the r0 inter-block-overlap mechanism, doubled)
//  - grid 1024 = exactly 4/CU; bijective XCD swizzle (1024%8==0)
//  - bank swizzle chunk ^= (row>>1)&3: every consecutive-8-lane service group
//    of a ds_read_b128 covers all 8 16B column slots (old scheme folded 64
//    lanes onto 4 slots -> the measured ~4 extra cy/read)
//  - counted vmcnt depth-2 pipeline (4 gloads/thread/stage -> vmcnt(4))

__global__ void __launch_bounds__(256, 4) gemm_mx(
    const uint8_t* __restrict__ Aq, const uint8_t* __restrict__ Bq,
    const float* __restrict__ bias, float* __restrict__ out,
    const unsigned* __restrict__ amax) {
  constexpr int K = 2048, N = 2048, BK = 64, ITERS = K / BK;
  __shared__ alignas(16) uint8_t sA[2][128 * BK];  // 2 x 8 KB
  __shared__ alignas(16) uint8_t sB[2][128 * BK];  // 2 x 8 KB

  const int tid = threadIdx.x;
  const int lane = tid & 63;
  const int wid = tid >> 6;               // 0..3
  const int wy = wid >> 1, wx = wid & 1;  // 2x2 waves -> 64x64 per wave

  // T1: bijective XCD-chunk swizzle (nwg=1024, 1024%8==0). r3-verified
  // mechanism (FETCH 67.6 -> 24.7 MB at 256^2).
  const int orig = (int)blockIdx.y * (int)gridDim.x + (int)blockIdx.x;
  const int wg = (orig & 7) * 128 + (orig >> 3);
  const long tileM = (long)(wg >> 4) * 128;  // 64 tile-rows
  const long tileN = (long)(wg & 15) * 128;  // 16 tile-cols

  v16f acc[2][2];
#pragma unroll
  for (int i = 0; i < 2; ++i)
#pragma unroll
    for (int j = 0; j < 2; ++j) acc[i][j] = (v16f)(0.f);

  // staging: granule g = s*256 + t  <->  LDS offset g*16
  //   row = g>>2 = s*64 + (t>>2), phys chunk = t&3,
  //   source logical chunk = (t&3) ^ ((row>>1)&3) = (t&3) ^ ((t>>3)&3)
  //   (s*64 doesn't touch row bits 1..2)
  const int clog = (tid & 3) ^ ((tid >> 3) & 3);
  const uint8_t* gA = Aq + (tileM + (tid >> 2)) * K + clog * 16;
  const uint8_t* gB = Bq + (tileN + (tid >> 2)) * K + clog * 16;

  // fragment reads: lane l holds row r=l&31, k = q*32..q*32+31 (q=l>>5),
  // as two b128 at logical chunks 2q, 2q+1; phys = log ^ ((r>>1)&3).
  const int r = lane & 31, q = lane >> 5;
  const int sw2 = (r >> 1) & 3;
  int aoff[2][2], boff[2][2];
#pragma unroll
  for (int ti = 0; ti < 2; ++ti)
#pragma unroll
    for (int cb = 0; cb < 2; ++cb) {
      aoff[ti][cb] = (wy * 64 + ti * 32 + r) * BK + 16 * (((q << 1) | cb) ^ sw2);
      boff[ti][cb] = (wx * 64 + ti * 32 + r) * BK + 16 * (((q << 1) | cb) ^ sw2);
    }

  auto stage = [&](int buf, int k0) {
#pragma unroll
    for (int s = 0; s < 2; ++s) {
      gload_lds16(gA + (long)s * 64 * K + k0, &sA[buf][s * 4096 + tid * 16]);
      gload_lds16(gB + (long)s * 64 * K + k0, &sB[buf][s * 4096 + tid * 16]);
    }
  };

  // prologue: depth-2 prefetch (8 loads/thread in flight)
  stage(0, 0);
  stage(1, BK);

  union Frag { v8i v; uint4 h[2]; };

  for (int it = 0; it < ITERS; ++it) {
    const int cur = it & 1;

    // stage(it) landed iff outstanding <= stage(it+1)'s 4 (FIFO)
    if (it + 1 < ITERS)
      asm volatile("s_waitcnt vmcnt(4)" ::: "memory");
    else
      asm volatile("s_waitcnt vmcnt(0)" ::: "memory");
    __builtin_amdgcn_s_barrier();       // all waves' share of tile(it) visible
    __builtin_amdgcn_sched_barrier(0);  // pin reads below the barrier

    const uint8_t* bufA = sA[cur];
    const uint8_t* bufB = sB[cur];

    Frag a[2], b[2];
#pragma unroll
    for (int ti = 0; ti < 2; ++ti) {
      b[ti].h[0] = *(const uint4*)(bufB + boff[ti][0]);
      b[ti].h[1] = *(const uint4*)(bufB + boff[ti][1]);
      a[ti].h[0] = *(const uint4*)(bufA + aoff[ti][0]);
      a[ti].h[1] = *(const uint4*)(bufA + aoff[ti][1]);
    }

    __builtin_amdgcn_s_setprio(1);
#pragma unroll
    for (int ti = 0; ti < 2; ++ti)
#pragma unroll
      for (int tj = 0; tj < 2; ++tj)
        acc[ti][tj] = __builtin_amdgcn_mfma_scale_f32_32x32x64_f8f6f4(
            a[ti].v, b[tj].v, acc[ti][tj], /*cbsz=fp8*/ 0, /*blgp=fp8*/ 0,
            /*opsel_a*/ 0, 0x7F7F7F7F, /*opsel_b*/ 0, 0x7F7F7F7F);  // e8m0 x1.0
    __builtin_amdgcn_s_setprio(0);

    // buf(cur) read-complete across all waves, then overwrite it for it+2
    if (it + 2 < ITERS) {
      asm volatile("s_waitcnt lgkmcnt(0)" ::: "memory");
      __builtin_amdgcn_s_barrier();
      stage(cur, (it + 2) * BK);
    }
  }

  // epilogue: 32x32 C/D layout col=lane&31, row=(reg&3)+8*(reg>>2)+4*(lane>>5)
  const float ax = __uint_as_float(amax[0]);
  const float aw = __uint_as_float(amax[1]);
  const float scale = (ax / FP8_DENOM) * (fmaxf(ax, aw) / FP8_DENOM);
#pragma unroll
  for (int tj = 0; tj < 2; ++tj) {
    const long col = tileN + wx * 64 + tj * 32 + r;
    const float bv = bias[col];
#pragma unroll
    for (int ti = 0; ti < 2; ++ti) {
      const long rowbase = tileM + wy * 64 + ti * 32 + 4 * q;
#pragma unroll
      for (int g = 0; g < 4; ++g)
#pragma unroll
        for (int rr = 0; rr < 4; ++rr)
          out[(rowbase + 8 * g + rr) * N + col] = acc[ti][tj][g * 4 + rr] * scale + bv;
    }
  }
}

// ---------- launch ----------

extern "C" void kernel_launch(void* const* d_in, const int* in_sizes, int n_in,
                              void* d_out, int out_size, void* d_ws, size_t ws_size,
                              hipStream_t stream) {
  const float* x = (const float*)d_in[0];     // [4,2048,2048] -> [8192,2048]
  const float* w = (const float*)d_in[1];     // [2048,2048]
  const float* bias = (const float*)d_in[2];  // [2048]
  float* out = (float*)d_out;                 // [8192,2048] fp32

  const int M = 8192, N = 2048, K = 2048;
  const long nx = (long)M * K;

  // ws layout: [0,8): amax bits (x,w); [8192, 8192+nx): xq codes; then wq codes.
  unsigned* amax = (unsigned*)d_ws;
  uint8_t* xq = (uint8_t*)d_ws + 8192;
  uint8_t* wq = xq + nx;

  hipMemsetAsync(amax, 0, 8, stream);  // graph-capturable
  amax_part<<<1280, 256, 0, stream>>>((const float4*)x, (const float4*)w, amax);
  quant2_kernel<<<5120, 256, 0, stream>>>((const float4*)x, (unsigned*)xq,
                                          (const float4*)w, (unsigned*)wq, amax);
  gemm_mx<<<dim3(N / 128, M / 128), 256, 0, stream>>>(xq, wq, bias, out, amax);
}